// Round 3
// baseline (390.560 us; speedup 1.0000x reference)
//
#include <hip/hip_runtime.h>
#include <hip/hip_bf16.h>

#define T_STEPS 100
#define BATCH   256
#define IN_DIM  784
#define HID_DIM 1024
#define OUT_DIM 10
#define M_ROWS  (T_STEPS * BATCH)   // 25600
#define KPAD    800                 // IN_DIM padded to multiple of 32
#define DECAY   0.6f
#define THRESH  0.9f

typedef __attribute__((ext_vector_type(8))) short bf16x8;
typedef __attribute__((ext_vector_type(4))) float f32x4;

// ---------------------------------------------------------------------------
// W1 transpose + hi/lo bf16 split:  W1[784][1024] fp32
//   -> Th[1024][800] bf16 (W_hi), Tl[1024][800] bf16 (W - W_hi)
// x in {0,1} is exact in bf16 -> x@Wh + x@Wl reproduces fp32 GEMM to ~1e-5.
// ---------------------------------------------------------------------------
__global__ __launch_bounds__(256) void w1_split_T(const float* __restrict__ W1,
                                                  unsigned short* __restrict__ Th,
                                                  unsigned short* __restrict__ Tl) {
    __shared__ unsigned short lh[32][33];
    __shared__ unsigned short ll[32][33];
    const int nb = blockIdx.x * 32;
    const int kb = blockIdx.y * 32;
    const int t  = threadIdx.x;
    const int ln = t & 31, lk = t >> 5;
    #pragma unroll
    for (int i = 0; i < 4; ++i) {
        const int k = kb + lk + i * 8;
        const float w = (k < IN_DIM) ? W1[(size_t)k * HID_DIM + nb + ln] : 0.f;
        __hip_bfloat16 h = __float2bfloat16(w);
        float hf = __bfloat162float(h);
        __hip_bfloat16 l = __float2bfloat16(w - hf);
        lh[lk + i * 8][ln] = __builtin_bit_cast(unsigned short, h);
        ll[lk + i * 8][ln] = __builtin_bit_cast(unsigned short, l);
    }
    __syncthreads();
    const int o_n = t >> 3;
    const int o_k = (t & 7) * 4;
    ushort4 vh, vl;
    vh.x = lh[o_k + 0][o_n]; vh.y = lh[o_k + 1][o_n];
    vh.z = lh[o_k + 2][o_n]; vh.w = lh[o_k + 3][o_n];
    vl.x = ll[o_k + 0][o_n]; vl.y = ll[o_k + 1][o_n];
    vl.z = ll[o_k + 2][o_n]; vl.w = ll[o_k + 3][o_n];
    *(ushort4*)&Th[(size_t)(nb + o_n) * KPAD + kb + o_k] = vh;
    *(ushort4*)&Tl[(size_t)(nb + o_n) * KPAD + kb + o_k] = vl;
}

// ---------------------------------------------------------------------------
// GEMM1 (MFMA): C[25600 x 1024] = X @ (Th + Tl)
// 128x128 tile, BK=32, 4 waves x (64x64 = 4x4 of 16x16x32).
// A: LDS, unpadded 64-B rows (m97 layout), double-buffered, 1 barrier/iter.
// B: direct global->register fragments (Th/Tl are 3.3 MB, L2-resident;
//    each b128 load touches 16 x 64 B fully-dense lines).
// ---------------------------------------------------------------------------
__global__ __launch_bounds__(256, 3) void gemm1_mfma(const float* __restrict__ X,
                                                     const unsigned short* __restrict__ Th,
                                                     const unsigned short* __restrict__ Tl,
                                                     float* __restrict__ C) {
    __shared__ unsigned short As[2][128 * 32];   // 8 KB x 2

    const int tid  = threadIdx.x;
    const int m0   = blockIdx.y * 128;
    const int n0   = blockIdx.x * 128;
    const int lane = tid & 63, wv = tid >> 6;
    const int wm   = (wv & 1) * 64, wn = (wv >> 1) * 64;
    const int ml   = lane & 15, quad = lane >> 4;

    // A staging: thread t -> row r = t>>1 (0..127), k-half h = (t&1)*16.
    // LDS offset = r*32 + h  -> linear in tid (optimal write pattern).
    const int s_r = tid >> 1;
    const int s_h = (tid & 1) * 16;
    const float* xrow = X + (size_t)(m0 + s_r) * IN_DIM + s_h;

    f32x4 acc[4][4];
    #pragma unroll
    for (int i = 0; i < 4; ++i)
        #pragma unroll
        for (int j = 0; j < 4; ++j)
            acc[i][j] = (f32x4){0.f, 0.f, 0.f, 0.f};

    // ---- prologue: stage kt=0 into buffer 0 ----
    {
        float4 x0 = *(const float4*)&xrow[0];
        float4 x1 = *(const float4*)&xrow[4];
        float4 x2 = *(const float4*)&xrow[8];
        float4 x3 = *(const float4*)&xrow[12];
        unsigned int p[8];
        const float* xf = &x0.x;   // x0..x3 contiguous on stack? avoid: pack explicitly
        (void)xf;
        p[0] = __builtin_amdgcn_perm(__builtin_bit_cast(unsigned int, x0.y), __builtin_bit_cast(unsigned int, x0.x), 0x07060302u);
        p[1] = __builtin_amdgcn_perm(__builtin_bit_cast(unsigned int, x0.w), __builtin_bit_cast(unsigned int, x0.z), 0x07060302u);
        p[2] = __builtin_amdgcn_perm(__builtin_bit_cast(unsigned int, x1.y), __builtin_bit_cast(unsigned int, x1.x), 0x07060302u);
        p[3] = __builtin_amdgcn_perm(__builtin_bit_cast(unsigned int, x1.w), __builtin_bit_cast(unsigned int, x1.z), 0x07060302u);
        p[4] = __builtin_amdgcn_perm(__builtin_bit_cast(unsigned int, x2.y), __builtin_bit_cast(unsigned int, x2.x), 0x07060302u);
        p[5] = __builtin_amdgcn_perm(__builtin_bit_cast(unsigned int, x2.w), __builtin_bit_cast(unsigned int, x2.z), 0x07060302u);
        p[6] = __builtin_amdgcn_perm(__builtin_bit_cast(unsigned int, x3.y), __builtin_bit_cast(unsigned int, x3.x), 0x07060302u);
        p[7] = __builtin_amdgcn_perm(__builtin_bit_cast(unsigned int, x3.w), __builtin_bit_cast(unsigned int, x3.z), 0x07060302u);
        *(uint4*)&As[0][s_r * 32 + s_h + 0] = *(uint4*)&p[0];
        *(uint4*)&As[0][s_r * 32 + s_h + 8] = *(uint4*)&p[4];
    }
    __syncthreads();

    for (int it = 0; it < KPAD / 32; ++it) {
        const int kt  = it * 32;
        const int cur = it & 1, nxt = cur ^ 1;

        // ---- B fragments direct from global (L2-resident) ----
        bf16x8 bh[4], bl[4];
        #pragma unroll
        for (int j = 0; j < 4; ++j) {
            const size_t g = (size_t)(n0 + wn + j * 16 + ml) * KPAD + kt + quad * 8;
            bh[j] = *(const bf16x8*)&Th[g];
            bl[j] = *(const bf16x8*)&Tl[g];
        }
        // ---- A fragments from LDS (current buffer) ----
        bf16x8 af[4];
        #pragma unroll
        for (int i = 0; i < 4; ++i)
            af[i] = *(const bf16x8*)&As[cur][(wm + i * 16 + ml) * 32 + quad * 8];

        // ---- issue next stage's global loads (latency hidden by MFMA) ----
        float4 x0, x1, x2, x3;
        bool have_next = (it + 1 < KPAD / 32);
        if (have_next) {
            const int kn = kt + 32;
            if (kn + s_h < IN_DIM) {
                x0 = *(const float4*)&xrow[kn + 0];
                x1 = *(const float4*)&xrow[kn + 4];
                x2 = *(const float4*)&xrow[kn + 8];
                x3 = *(const float4*)&xrow[kn + 12];
            } else {
                x0 = x1 = x2 = x3 = make_float4(0.f, 0.f, 0.f, 0.f);
            }
        }

        // ---- MFMA ----
        #pragma unroll
        for (int i = 0; i < 4; ++i)
            #pragma unroll
            for (int j = 0; j < 4; ++j) {
                acc[i][j] = __builtin_amdgcn_mfma_f32_16x16x32_bf16(af[i], bh[j], acc[i][j], 0, 0, 0);
                acc[i][j] = __builtin_amdgcn_mfma_f32_16x16x32_bf16(af[i], bl[j], acc[i][j], 0, 0, 0);
            }

        // ---- write next buffer, one barrier per iter ----
        if (have_next) {
            unsigned int p[8];
            p[0] = __builtin_amdgcn_perm(__builtin_bit_cast(unsigned int, x0.y), __builtin_bit_cast(unsigned int, x0.x), 0x07060302u);
            p[1] = __builtin_amdgcn_perm(__builtin_bit_cast(unsigned int, x0.w), __builtin_bit_cast(unsigned int, x0.z), 0x07060302u);
            p[2] = __builtin_amdgcn_perm(__builtin_bit_cast(unsigned int, x1.y), __builtin_bit_cast(unsigned int, x1.x), 0x07060302u);
            p[3] = __builtin_amdgcn_perm(__builtin_bit_cast(unsigned int, x1.w), __builtin_bit_cast(unsigned int, x1.z), 0x07060302u);
            p[4] = __builtin_amdgcn_perm(__builtin_bit_cast(unsigned int, x2.y), __builtin_bit_cast(unsigned int, x2.x), 0x07060302u);
            p[5] = __builtin_amdgcn_perm(__builtin_bit_cast(unsigned int, x2.w), __builtin_bit_cast(unsigned int, x2.z), 0x07060302u);
            p[6] = __builtin_amdgcn_perm(__builtin_bit_cast(unsigned int, x3.y), __builtin_bit_cast(unsigned int, x3.x), 0x07060302u);
            p[7] = __builtin_amdgcn_perm(__builtin_bit_cast(unsigned int, x3.w), __builtin_bit_cast(unsigned int, x3.z), 0x07060302u);
            *(uint4*)&As[nxt][s_r * 32 + s_h + 0] = *(uint4*)&p[0];
            *(uint4*)&As[nxt][s_r * 32 + s_h + 8] = *(uint4*)&p[4];
        }
        __syncthreads();
    }

    // epilogue: C/D layout col=lane&15, row=quad*4+reg
    #pragma unroll
    for (int i = 0; i < 4; ++i)
        #pragma unroll
        for (int j = 0; j < 4; ++j) {
            const int row = m0 + wm + i * 16 + quad * 4;
            const int col = n0 + wn + j * 16 + ml;
            #pragma unroll
            for (int r = 0; r < 4; ++r)
                C[(size_t)(row + r) * HID_DIM + col] = acc[i][j][r];
        }
}

// ---------------------------------------------------------------------------
// LIF1 fused with GEMM2: scan hidden membranes, write spikes in place,
// and (rarely — threshold is ~4.7 sigma, ~tens of spikes in 26M samples)
// scatter W2 rows into pre-zeroed outu via atomics. Exact for any density.
// ---------------------------------------------------------------------------
__global__ __launch_bounds__(256) void lif1_fused(float* __restrict__ hid,
                                                  const float* __restrict__ W2,
                                                  float* __restrict__ outu) {
    const int idx = blockIdx.x * blockDim.x + threadIdx.x;   // 0..65535
    float4* h4 = (float4*)hid;
    const int stride4 = (BATCH * HID_DIM) / 4;               // 65536
    const int b  = (idx * 4) >> 10;                          // batch index
    const int h0 = (idx * 4) & 1023;                         // first hidden idx

    float4 mem = make_float4(0.f, 0.f, 0.f, 0.f);
    float4 u_next = h4[idx];                                 // t = 0 prefetch
    for (int t = 0; t < T_STEPS; ++t) {
        float4 u = u_next;
        if (t + 1 < T_STEPS) u_next = h4[(t + 1) * stride4 + idx];
        float4 s;
        mem.x = mem.x * DECAY + u.x; s.x = (mem.x >= THRESH) ? 1.f : 0.f; mem.x -= s.x * THRESH;
        mem.y = mem.y * DECAY + u.y; s.y = (mem.y >= THRESH) ? 1.f : 0.f; mem.y -= s.y * THRESH;
        mem.z = mem.z * DECAY + u.z; s.z = (mem.z >= THRESH) ? 1.f : 0.f; mem.z -= s.z * THRESH;
        mem.w = mem.w * DECAY + u.w; s.w = (mem.w >= THRESH) ? 1.f : 0.f; mem.w -= s.w * THRESH;
        h4[t * stride4 + idx] = s;
        if (s.x + s.y + s.z + s.w > 0.f) {                   // ~never taken
            float* od = outu + (size_t)t * (BATCH * OUT_DIM) + b * OUT_DIM;
            #pragma unroll
            for (int c = 0; c < 4; ++c) {
                const float sv = (&s.x)[c];
                if (sv != 0.f) {
                    const float* w = W2 + (size_t)(h0 + c) * OUT_DIM;
                    #pragma unroll
                    for (int o = 0; o < OUT_DIM; ++o) atomicAdd(&od[o], w[o]);
                }
            }
        }
    }
}

// ---------------------------------------------------------------------------
// LIF2: scan output membranes in place; loads are state-independent ->
// 4-deep prefetch hides the serial-scan latency.
// ---------------------------------------------------------------------------
__global__ __launch_bounds__(256) void lif2(float* __restrict__ outp) {
    const int n = blockIdx.x * blockDim.x + threadIdx.x;
    const int stride = BATCH * OUT_DIM;                      // 2560
    if (n >= stride) return;
    float mem = 0.f;
    float u[4];
    #pragma unroll
    for (int c = 0; c < 4; ++c) u[c] = outp[c * stride + n];
    for (int t = 0; t < T_STEPS; t += 4) {
        float nu[4];
        if (t + 4 < T_STEPS) {
            #pragma unroll
            for (int c = 0; c < 4; ++c) nu[c] = outp[(t + 4 + c) * stride + n];
        }
        #pragma unroll
        for (int c = 0; c < 4; ++c) {
            mem = mem * DECAY + u[c];
            float s = (mem >= THRESH) ? 1.f : 0.f;
            mem -= s * THRESH;
            outp[(t + c) * stride + n] = s;
        }
        #pragma unroll
        for (int c = 0; c < 4; ++c) u[c] = nu[c];
    }
}

extern "C" void kernel_launch(void* const* d_in, const int* in_sizes, int n_in,
                              void* d_out, int out_size, void* d_ws, size_t ws_size,
                              hipStream_t stream) {
    const float* x  = (const float*)d_in[0];   // [T, B, I]
    const float* W1 = (const float*)d_in[1];   // [I, H]
    const float* W2 = (const float*)d_in[2];   // [H, O]
    float* out  = (float*)d_out;
    float* hid  = out;                                    // [T*B, H]
    float* outu = out + (size_t)M_ROWS * HID_DIM;         // [T*B, O]

    unsigned short* Th = (unsigned short*)d_ws;           // [1024][800] bf16
    unsigned short* Tl = Th + (size_t)HID_DIM * KPAD;     // [1024][800] bf16

    dim3 gt(HID_DIM / 32, KPAD / 32);
    w1_split_T<<<gt, 256, 0, stream>>>(W1, Th, Tl);

    // zero the output-potential region (atomic accumulation target)
    hipMemsetAsync(outu, 0, (size_t)M_ROWS * OUT_DIM * sizeof(float), stream);

    dim3 g1(HID_DIM / 128, M_ROWS / 128);                 // (8, 200)
    gemm1_mfma<<<g1, 256, 0, stream>>>(x, Th, Tl, hid);

    lif1_fused<<<(BATCH * HID_DIM / 4) / 256, 256, 0, stream>>>(hid, W2, outu);

    lif2<<<(BATCH * OUT_DIM + 255) / 256, 256, 0, stream>>>(outu);
}

// Round 5
// 303.219 us; speedup vs baseline: 1.2880x; 1.2880x over previous
//
#include <hip/hip_runtime.h>
#include <hip/hip_bf16.h>

#define T_STEPS 100
#define BATCH   256
#define IN_DIM  784
#define HID_DIM 1024
#define OUT_DIM 10
#define M_ROWS  (T_STEPS * BATCH)   // 25600
#define KPAD    800                 // IN_DIM padded to multiple of 32
#define DECAY   0.6f
#define THRESH  0.9f

typedef __attribute__((ext_vector_type(8))) short bf16x8;
typedef __attribute__((ext_vector_type(4))) float f32x4;

// pack 8 fp32 (two float4) -> 8 bf16 (uint4) by truncation; exact for {0,1}
#define PACK8(dstp, v0, v1)                                                                        \
    {                                                                                              \
        unsigned int p0 = __builtin_amdgcn_perm(__builtin_bit_cast(unsigned int, (v0).y),          \
                                                __builtin_bit_cast(unsigned int, (v0).x), 0x07060302u); \
        unsigned int p1 = __builtin_amdgcn_perm(__builtin_bit_cast(unsigned int, (v0).w),          \
                                                __builtin_bit_cast(unsigned int, (v0).z), 0x07060302u); \
        unsigned int p2 = __builtin_amdgcn_perm(__builtin_bit_cast(unsigned int, (v1).y),          \
                                                __builtin_bit_cast(unsigned int, (v1).x), 0x07060302u); \
        unsigned int p3 = __builtin_amdgcn_perm(__builtin_bit_cast(unsigned int, (v1).w),          \
                                                __builtin_bit_cast(unsigned int, (v1).z), 0x07060302u); \
        *(uint4*)(dstp) = make_uint4(p0, p1, p2, p3);                                              \
    }

// ---------------------------------------------------------------------------
// W1 transpose + hi/lo bf16 split:  W1[784][1024] fp32
//   -> Th[1024][800] bf16 (W_hi), Tl[1024][800] bf16 (W - W_hi); k>=784 zeroed.
// x in {0,1} is exact in bf16 -> x@Wh + x@Wl reproduces fp32 GEMM to ~1e-5.
// ---------------------------------------------------------------------------
__global__ __launch_bounds__(256) void w1_split_T(const float* __restrict__ W1,
                                                  unsigned short* __restrict__ Th,
                                                  unsigned short* __restrict__ Tl) {
    __shared__ unsigned short lh[32][33];
    __shared__ unsigned short ll[32][33];
    const int nb = blockIdx.x * 32;
    const int kb = blockIdx.y * 32;
    const int t  = threadIdx.x;
    const int ln = t & 31, lk = t >> 5;
    #pragma unroll
    for (int i = 0; i < 4; ++i) {
        const int k = kb + lk + i * 8;
        const float w = (k < IN_DIM) ? W1[(size_t)k * HID_DIM + nb + ln] : 0.f;
        __hip_bfloat16 h = __float2bfloat16(w);
        float hf = __bfloat162float(h);
        __hip_bfloat16 l = __float2bfloat16(w - hf);
        lh[lk + i * 8][ln] = __builtin_bit_cast(unsigned short, h);
        ll[lk + i * 8][ln] = __builtin_bit_cast(unsigned short, l);
    }
    __syncthreads();
    const int o_n = t >> 3;
    const int o_k = (t & 7) * 4;
    ushort4 vh, vl;
    vh.x = lh[o_k + 0][o_n]; vh.y = lh[o_k + 1][o_n];
    vh.z = lh[o_k + 2][o_n]; vh.w = lh[o_k + 3][o_n];
    vl.x = ll[o_k + 0][o_n]; vl.y = ll[o_k + 1][o_n];
    vl.z = ll[o_k + 2][o_n]; vl.w = ll[o_k + 3][o_n];
    *(ushort4*)&Th[(size_t)(nb + o_n) * KPAD + kb + o_k] = vh;
    *(ushort4*)&Tl[(size_t)(nb + o_n) * KPAD + kb + o_k] = vl;
}

// ---------------------------------------------------------------------------
// GEMM1 (MFMA): C[25600 x 1024] = X @ (Th + Tl)
// 128x128 tile, BK=32, 4 waves x (64x64 = 4x4 of 16x16x32).
// All tiles in LDS, unpadded 64-B rows with XOR chunk swizzle
//   slot = chunk ^ ((row>>1)&3)   [same formula on write & read -> correct
//   by construction; makes every b128 access 2-way bank-aliased = free]
// Register-prefetch of next K-tile before the MFMAs (R3-proven pattern),
// single LDS buffer, 2 barriers/iter.
// Block swizzle: bid%8 (hw XCD round-robin) owns a contiguous m-partition.
// ---------------------------------------------------------------------------
__global__ __launch_bounds__(256, 3) void gemm1_mfma(const float* __restrict__ X,
                                                     const unsigned short* __restrict__ Th,
                                                     const unsigned short* __restrict__ Tl,
                                                     float* __restrict__ C) {
    __shared__ unsigned short As[128 * 32];    // 8 KB
    __shared__ unsigned short Bhs[128 * 32];   // 8 KB
    __shared__ unsigned short Bls[128 * 32];   // 8 KB

    const int tid = threadIdx.x;
    const int bid = blockIdx.x;
    const int xcd = bid & 7;
    const int j_  = bid >> 3;                  // 0..199
    const int m0  = (xcd * 25 + (j_ >> 3)) * 128;
    const int n0  = (j_ & 7) * 128;

    const int lane = tid & 63, wv = tid >> 6;
    const int wm   = (wv & 1) * 64, wn = (wv >> 1) * 64;
    const int ml   = lane & 15, quad = lane >> 4;

    // staging: thread t -> rows sr, sr+64; chunk sc (8 elems = 16 B)
    const int sr = tid >> 2;                   // 0..63
    const int sc = tid & 3;
    const int f0 = (sr >> 1) & 3;              // note f(sr+64) == f(sr)
    const int w0 = sr * 32 + ((sc ^ f0) * 8);
    const int w1 = (sr + 64) * 32 + ((sc ^ f0) * 8);

    const float*          Xa = X  + (size_t)(m0 + sr)      * IN_DIM + sc * 8;
    const float*          Xb = X  + (size_t)(m0 + sr + 64) * IN_DIM + sc * 8;
    const unsigned short* Ha = Th + (size_t)(n0 + sr)      * KPAD   + sc * 8;
    const unsigned short* Hb = Th + (size_t)(n0 + sr + 64) * KPAD   + sc * 8;
    const unsigned short* La = Tl + (size_t)(n0 + sr)      * KPAD   + sc * 8;
    const unsigned short* Lb = Tl + (size_t)(n0 + sr + 64) * KPAD   + sc * 8;

    f32x4 acc[4][4];
    #pragma unroll
    for (int i = 0; i < 4; ++i)
        #pragma unroll
        for (int j = 0; j < 4; ++j)
            acc[i][j] = (f32x4){0.f, 0.f, 0.f, 0.f};

    // ---- prologue: load + store K-tile 0 (cols sc*8..sc*8+7 < 784 always) ----
    float4 xa0 = *(const float4*)&Xa[0], xa1 = *(const float4*)&Xa[4];
    float4 xb0 = *(const float4*)&Xb[0], xb1 = *(const float4*)&Xb[4];
    uint4  vh0 = *(const uint4*)&Ha[0],  vh1 = *(const uint4*)&Hb[0];
    uint4  vl0 = *(const uint4*)&La[0],  vl1 = *(const uint4*)&Lb[0];
    PACK8(&As[w0], xa0, xa1);
    PACK8(&As[w1], xb0, xb1);
    *(uint4*)&Bhs[w0] = vh0;  *(uint4*)&Bhs[w1] = vh1;
    *(uint4*)&Bls[w0] = vl0;  *(uint4*)&Bls[w1] = vl1;
    __syncthreads();

    for (int it = 0; it < KPAD / 32; ++it) {
        // ---- fragments from LDS (swizzled read = inverse of write) ----
        bf16x8 af[4], bh[4], bl[4];
        #pragma unroll
        for (int i = 0; i < 4; ++i) {
            const int m = wm + i * 16 + ml;
            af[i] = *(const bf16x8*)&As[m * 32 + ((quad ^ ((m >> 1) & 3)) * 8)];
        }
        #pragma unroll
        for (int j = 0; j < 4; ++j) {
            const int n   = wn + j * 16 + ml;
            const int idx = n * 32 + ((quad ^ ((n >> 1) & 3)) * 8);
            bh[j] = *(const bf16x8*)&Bhs[idx];
            bl[j] = *(const bf16x8*)&Bls[idx];
        }

        // ---- register-prefetch next K-tile (latency hidden under MFMAs) ----
        const bool have_next = (it + 1 < KPAD / 32);
        if (have_next) {
            const int kt = (it + 1) * 32;
            const int c0 = kt + sc * 8;
            const bool v0 = (c0 < IN_DIM), v1 = (c0 + 4 < IN_DIM);
            xa0 = v0 ? *(const float4*)&Xa[kt]     : make_float4(0.f, 0.f, 0.f, 0.f);
            xa1 = v1 ? *(const float4*)&Xa[kt + 4] : make_float4(0.f, 0.f, 0.f, 0.f);
            xb0 = v0 ? *(const float4*)&Xb[kt]     : make_float4(0.f, 0.f, 0.f, 0.f);
            xb1 = v1 ? *(const float4*)&Xb[kt + 4] : make_float4(0.f, 0.f, 0.f, 0.f);
            vh0 = *(const uint4*)&Ha[kt];  vh1 = *(const uint4*)&Hb[kt];
            vl0 = *(const uint4*)&La[kt];  vl1 = *(const uint4*)&Lb[kt];
        }

        // ---- MFMA ----
        #pragma unroll
        for (int i = 0; i < 4; ++i)
            #pragma unroll
            for (int j = 0; j < 4; ++j) {
                acc[i][j] = __builtin_amdgcn_mfma_f32_16x16x32_bf16(af[i], bh[j], acc[i][j], 0, 0, 0);
                acc[i][j] = __builtin_amdgcn_mfma_f32_16x16x32_bf16(af[i], bl[j], acc[i][j], 0, 0, 0);
            }

        __syncthreads();   // all frag reads done before overwrite
        if (have_next) {
            PACK8(&As[w0], xa0, xa1);
            PACK8(&As[w1], xb0, xb1);
            *(uint4*)&Bhs[w0] = vh0;  *(uint4*)&Bhs[w1] = vh1;
            *(uint4*)&Bls[w0] = vl0;  *(uint4*)&Bls[w1] = vl1;
            __syncthreads();
        }
    }

    // epilogue: C/D layout col=lane&15, row=quad*4+reg
    #pragma unroll
    for (int i = 0; i < 4; ++i)
        #pragma unroll
        for (int j = 0; j < 4; ++j) {
            const int row = m0 + wm + i * 16 + quad * 4;
            const int col = n0 + wn + j * 16 + ml;
            #pragma unroll
            for (int r = 0; r < 4; ++r)
                C[(size_t)(row + r) * HID_DIM + col] = acc[i][j][r];
        }
}

// ---------------------------------------------------------------------------
// LIF1 fused with GEMM2: scan hidden membranes, write spikes in place,
// and (rarely — threshold ~4.7 sigma) scatter W2 rows into pre-zeroed outu
// via atomics. Exact for any spike density. 4-deep load prefetch.
// ---------------------------------------------------------------------------
__global__ __launch_bounds__(256) void lif1_fused(float* __restrict__ hid,
                                                  const float* __restrict__ W2,
                                                  float* __restrict__ outu) {
    const int idx = blockIdx.x * blockDim.x + threadIdx.x;   // 0..65535
    float4* h4 = (float4*)hid;
    const int stride4 = (BATCH * HID_DIM) / 4;               // 65536
    const int b  = (idx * 4) >> 10;
    const int h0 = (idx * 4) & 1023;

    float4 mem = make_float4(0.f, 0.f, 0.f, 0.f);
    float4 u[4];
    #pragma unroll
    for (int c = 0; c < 4; ++c) u[c] = h4[c * stride4 + idx];

    for (int t = 0; t < T_STEPS; t += 4) {
        float4 nu[4];
        if (t + 4 < T_STEPS) {
            #pragma unroll
            for (int c = 0; c < 4; ++c) nu[c] = h4[(t + 4 + c) * stride4 + idx];
        }
        #pragma unroll
        for (int c = 0; c < 4; ++c) {
            float4 uu = u[c];
            float4 s;
            mem.x = mem.x * DECAY + uu.x; s.x = (mem.x >= THRESH) ? 1.f : 0.f; mem.x -= s.x * THRESH;
            mem.y = mem.y * DECAY + uu.y; s.y = (mem.y >= THRESH) ? 1.f : 0.f; mem.y -= s.y * THRESH;
            mem.z = mem.z * DECAY + uu.z; s.z = (mem.z >= THRESH) ? 1.f : 0.f; mem.z -= s.z * THRESH;
            mem.w = mem.w * DECAY + uu.w; s.w = (mem.w >= THRESH) ? 1.f : 0.f; mem.w -= s.w * THRESH;
            h4[(t + c) * stride4 + idx] = s;
            if (s.x + s.y + s.z + s.w > 0.f) {               // ~never taken
                float* od = outu + (size_t)(t + c) * (BATCH * OUT_DIM) + b * OUT_DIM;
                #pragma unroll
                for (int e = 0; e < 4; ++e) {
                    const float sv = (&s.x)[e];
                    if (sv != 0.f) {
                        const float* w = W2 + (size_t)(h0 + e) * OUT_DIM;
                        #pragma unroll
                        for (int o = 0; o < OUT_DIM; ++o) atomicAdd(&od[o], w[o]);
                    }
                }
            }
        }
        #pragma unroll
        for (int c = 0; c < 4; ++c) u[c] = nu[c];
    }
}

// ---------------------------------------------------------------------------
// LIF2: scan output membranes in place; 4-deep prefetch hides serial latency.
// ---------------------------------------------------------------------------
__global__ __launch_bounds__(256) void lif2(float* __restrict__ outp) {
    const int n = blockIdx.x * blockDim.x + threadIdx.x;
    const int stride = BATCH * OUT_DIM;                      // 2560
    if (n >= stride) return;
    float mem = 0.f;
    float u[4];
    #pragma unroll
    for (int c = 0; c < 4; ++c) u[c] = outp[c * stride + n];
    for (int t = 0; t < T_STEPS; t += 4) {
        float nu[4];
        if (t + 4 < T_STEPS) {
            #pragma unroll
            for (int c = 0; c < 4; ++c) nu[c] = outp[(t + 4 + c) * stride + n];
        }
        #pragma unroll
        for (int c = 0; c < 4; ++c) {
            mem = mem * DECAY + u[c];
            float s = (mem >= THRESH) ? 1.f : 0.f;
            mem -= s * THRESH;
            outp[(t + c) * stride + n] = s;
        }
        #pragma unroll
        for (int c = 0; c < 4; ++c) u[c] = nu[c];
    }
}

extern "C" void kernel_launch(void* const* d_in, const int* in_sizes, int n_in,
                              void* d_out, int out_size, void* d_ws, size_t ws_size,
                              hipStream_t stream) {
    const float* x  = (const float*)d_in[0];   // [T, B, I]
    const float* W1 = (const float*)d_in[1];   // [I, H]
    const float* W2 = (const float*)d_in[2];   // [H, O]
    float* out  = (float*)d_out;
    float* hid  = out;                                    // [T*B, H]
    float* outu = out + (size_t)M_ROWS * HID_DIM;         // [T*B, O]

    unsigned short* Th = (unsigned short*)d_ws;           // [1024][800] bf16
    unsigned short* Tl = Th + (size_t)HID_DIM * KPAD;     // [1024][800] bf16

    dim3 gt(HID_DIM / 32, KPAD / 32);
    w1_split_T<<<gt, 256, 0, stream>>>(W1, Th, Tl);

    hipMemsetAsync(outu, 0, (size_t)M_ROWS * OUT_DIM * sizeof(float), stream);

    gemm1_mfma<<<1600, 256, 0, stream>>>(x, Th, Tl, hid);

    lif1_fused<<<(BATCH * HID_DIM / 4) / 256, 256, 0, stream>>>(hid, W2, outu);

    lif2<<<(BATCH * OUT_DIM + 255) / 256, 256, 0, stream>>>(outu);
}